// Round 1
// baseline (2019.495 us; speedup 1.0000x reference)
//
#include <hip/hip_runtime.h>

#define NPG 116          // nodes per graph
#define DEGC 32          // edges per node
#define EPG (NPG * DEGC) // 3712 edges per graph
#define HID 32
#define HID2 64
#define EPS 1e-5f

// ---------------------------------------------------------------------------
// ws layout (floats):
//   [0,256)    stats: s1[32] q1[32] s2[64] q2[64]
//   [256,512)  coefs: a1[32] c1[32] a2[64] c2[64]
//   [512,512+N)        dinv
//   [512+N, +32N)      h1   (lin1, then conv1 out, overwritten in place)
//   [.. +64N)          h2   (lin2, then conv2 out)
//   [.. +32*G)         z    (FC1 pre-BN)
// total = 512 + 97N + 32G floats  (~46.2 MB)
// ---------------------------------------------------------------------------

// Per-graph degree (at destination) + self loop, then dinv = rsqrt(deg).
// Block 0 also zeroes the stats accumulators (stream order protects later use).
__global__ __launch_bounds__(256) void k_deg(const int* __restrict__ ei,
                                             const float* __restrict__ ew,
                                             float* __restrict__ dinv,
                                             float* __restrict__ stats,
                                             int N, int E) {
  __shared__ float degs[NPG];
  int g = blockIdx.x, tid = threadIdx.x;
  if (g == 0 && tid < 256) stats[tid] = 0.0f;
  for (int i = tid; i < NPG; i += 256) degs[i] = 1.0f;  // self-loop weight
  __syncthreads();
  int e0 = g * EPG;
  int nb = g * NPG;
  const int* colp = ei + E;
  for (int e = tid; e < EPG; e += 256) {
    int d = colp[e0 + e] - nb;
    atomicAdd(&degs[d], ew[e0 + e]);
  }
  __syncthreads();
  for (int i = tid; i < NPG; i += 256) {
    float dg = degs[i];
    dinv[nb + i] = dg > 0.0f ? rsqrtf(dg) : 0.0f;
  }
}

// lin1 = x @ W1   (N x 116 @ 116 x 32), 64 rows per block
__global__ __launch_bounds__(256) void k_gemm1(const float* __restrict__ x,
                                               const float* __restrict__ W1,
                                               float* __restrict__ h1, int N) {
  __shared__ float xs[64][117];
  __shared__ float Ws[116 * 32];
  int tid = threadIdx.x;
  int r0 = blockIdx.x * 64;
  int nrows = min(64, N - r0);
  long base = (long)r0 * 116;
  for (int i = tid; i < nrows * 116; i += 256) {
    int r = i / 116, k = i - r * 116;
    xs[r][k] = x[base + i];
  }
  for (int i = tid; i < 116 * 32; i += 256) Ws[i] = W1[i];
  __syncthreads();
  int row = tid & 63, cg = tid >> 6;
  int c0 = cg * 8;
  if (row < nrows) {
    float acc[8];
#pragma unroll
    for (int j = 0; j < 8; ++j) acc[j] = 0.0f;
    for (int k = 0; k < 116; ++k) {
      float xv = xs[row][k];
#pragma unroll
      for (int j = 0; j < 8; ++j) acc[j] += xv * Ws[k * 32 + c0 + j];
    }
    float4* o = (float4*)&h1[(long)(r0 + row) * 32 + c0];
    o[0] = make_float4(acc[0], acc[1], acc[2], acc[3]);
    o[1] = make_float4(acc[4], acc[5], acc[6], acc[7]);
  }
}

// conv1 scatter per graph: out[dst] += lin[src]*norm  (+ self loop), then
// per-block BN stat partials -> global atomics. Overwrites h1 in place.
__global__ __launch_bounds__(256) void k_scat1(const int* __restrict__ ei,
                                               const float* __restrict__ ew,
                                               const float* __restrict__ dinv,
                                               float* __restrict__ h1,
                                               float* __restrict__ stats,
                                               int N, int E) {
  __shared__ float hs[NPG][HID];
  __shared__ float os[NPG][HID];
  __shared__ float dv[NPG];
  __shared__ float ss[HID], qs[HID];
  int g = blockIdx.x, tid = threadIdx.x;
  int nb = g * NPG;
  float* hbuf = h1 + (long)nb * HID;
  for (int i = tid; i < NPG * HID; i += 256) (&hs[0][0])[i] = hbuf[i];
  for (int i = tid; i < NPG; i += 256) dv[i] = dinv[nb + i];
  if (tid < HID) { ss[tid] = 0.0f; qs[tid] = 0.0f; }
  __syncthreads();
  for (int i = tid; i < NPG * HID; i += 256) {
    int n = i >> 5;
    (&os[0][0])[i] = (&hs[0][0])[i] * dv[n] * dv[n];  // self loop
  }
  __syncthreads();
  int c = tid & 31, slot = tid >> 5;  // 8 edge slots
  int e0 = g * EPG;
  const int* rowp = ei;
  const int* colp = ei + E;
  for (int e = slot; e < EPG; e += 8) {
    int eg = e0 + e;
    int s = rowp[eg] - nb;
    int d = colp[eg] - nb;
    float nrm = dv[s] * ew[eg] * dv[d];
    atomicAdd(&os[d][c], hs[s][c] * nrm);
  }
  __syncthreads();
  float s_ = 0.0f, q_ = 0.0f;
  for (int i = tid; i < NPG * HID; i += 256) {
    float v = (&os[0][0])[i];
    hbuf[i] = v;
    s_ += v; q_ += v * v;
  }
  atomicAdd(&ss[tid & 31], s_);
  atomicAdd(&qs[tid & 31], q_);
  __syncthreads();
  if (tid < HID) {
    atomicAdd(&stats[tid], ss[tid]);
    atomicAdd(&stats[32 + tid], qs[tid]);
  }
}

// BN coefficients: a = g*rsqrt(var+eps), c = beta - mean*a
__global__ void k_coef(const float* __restrict__ s, const float* __restrict__ q,
                       const float* __restrict__ gamma, const float* __restrict__ beta,
                       float* __restrict__ a, float* __restrict__ cc,
                       float invN, int C) {
  int c = threadIdx.x;
  if (c < C) {
    float m = s[c] * invN;
    float v = q[c] * invN - m * m;
    float aa = gamma[c] * rsqrtf(v + EPS);
    a[c] = aa;
    cc[c] = beta[c] - m * aa;
  }
}

// lin2 = relu(a1*h1+c1) @ W2   (N x 32 @ 32 x 64), 64 rows per block
__global__ __launch_bounds__(256) void k_gemm2(const float* __restrict__ h1,
                                               const float* __restrict__ W2,
                                               const float* __restrict__ coef,
                                               float* __restrict__ h2, int N) {
  __shared__ float ys[64][33];
  __shared__ float Ws[32 * 64];
  __shared__ float ac[64];
  int tid = threadIdx.x;
  int r0 = blockIdx.x * 64;
  int nrows = min(64, N - r0);
  if (tid < 64) ac[tid] = coef[tid];
  for (int i = tid; i < 32 * 64; i += 256) Ws[i] = W2[i];
  __syncthreads();
  long base = (long)r0 * 32;
  for (int i = tid; i < nrows * 32; i += 256) {
    int r = i >> 5, k = i & 31;
    float v = h1[base + i];
    ys[r][k] = fmaxf(0.0f, ac[k] * v + ac[32 + k]);
  }
  __syncthreads();
  int row = tid & 63, cg = tid >> 6;
  int c0 = cg * 16;
  if (row < nrows) {
    float acc[16];
#pragma unroll
    for (int j = 0; j < 16; ++j) acc[j] = 0.0f;
    for (int k = 0; k < 32; ++k) {
      float yv = ys[row][k];
#pragma unroll
      for (int j = 0; j < 16; ++j) acc[j] += yv * Ws[k * 64 + c0 + j];
    }
    float4* o = (float4*)&h2[(long)(r0 + row) * 64 + c0];
    o[0] = make_float4(acc[0], acc[1], acc[2], acc[3]);
    o[1] = make_float4(acc[4], acc[5], acc[6], acc[7]);
    o[2] = make_float4(acc[8], acc[9], acc[10], acc[11]);
    o[3] = make_float4(acc[12], acc[13], acc[14], acc[15]);
  }
}

// conv2 scatter per graph (64 channels, 2 per thread)
__global__ __launch_bounds__(256) void k_scat2(const int* __restrict__ ei,
                                               const float* __restrict__ ew,
                                               const float* __restrict__ dinv,
                                               float* __restrict__ h2,
                                               float* __restrict__ stats,
                                               int N, int E) {
  __shared__ float hs[NPG][HID2];
  __shared__ float os[NPG][HID2];
  __shared__ float dv[NPG];
  __shared__ float ss[HID2], qs[HID2];
  int g = blockIdx.x, tid = threadIdx.x;
  int nb = g * NPG;
  float* hbuf = h2 + (long)nb * HID2;
  for (int i = tid; i < NPG * HID2; i += 256) (&hs[0][0])[i] = hbuf[i];
  for (int i = tid; i < NPG; i += 256) dv[i] = dinv[nb + i];
  if (tid < HID2) { ss[tid] = 0.0f; qs[tid] = 0.0f; }
  __syncthreads();
  for (int i = tid; i < NPG * HID2; i += 256) {
    int n = i >> 6;
    (&os[0][0])[i] = (&hs[0][0])[i] * dv[n] * dv[n];
  }
  __syncthreads();
  int c = tid & 31, slot = tid >> 5;
  int e0 = g * EPG;
  const int* rowp = ei;
  const int* colp = ei + E;
  for (int e = slot; e < EPG; e += 8) {
    int eg = e0 + e;
    int s = rowp[eg] - nb;
    int d = colp[eg] - nb;
    float nrm = dv[s] * ew[eg] * dv[d];
    atomicAdd(&os[d][c], hs[s][c] * nrm);
    atomicAdd(&os[d][c + 32], hs[s][c + 32] * nrm);
  }
  __syncthreads();
  float s_ = 0.0f, q_ = 0.0f;
  for (int i = tid; i < NPG * HID2; i += 256) {
    float v = (&os[0][0])[i];
    hbuf[i] = v;
    s_ += v; q_ += v * v;
  }
  atomicAdd(&ss[tid & 63], s_);
  atomicAdd(&qs[tid & 63], q_);
  __syncthreads();
  if (tid < HID2) {
    atomicAdd(&stats[64 + tid], ss[tid]);
    atomicAdd(&stats[128 + tid], qs[tid]);
  }
}

// per-graph BN2+relu, mean/max pool, FC1 (emb[128] @ Wf1[128x32]) -> z
__global__ __launch_bounds__(256) void k_pool(const float* __restrict__ h2,
                                              const float* __restrict__ coef,
                                              const float* __restrict__ Wf1,
                                              float* __restrict__ z, int N) {
  __shared__ float emb[128];
  __shared__ float psum[4][64];
  __shared__ float pmax[4][64];
  int g = blockIdx.x, tid = threadIdx.x;
  int c = tid & 63, grp = tid >> 6;
  float a = coef[64 + c], b = coef[128 + c];
  long nb = (long)g * NPG;
  float s = 0.0f, mx = -1e30f;
  for (int n = grp; n < NPG; n += 4) {
    float v = h2[(nb + n) * 64 + c];
    float y = fmaxf(0.0f, a * v + b);
    s += y; mx = fmaxf(mx, y);
  }
  psum[grp][c] = s; pmax[grp][c] = mx;
  __syncthreads();
  if (tid < 64) {
    float S = psum[0][tid] + psum[1][tid] + psum[2][tid] + psum[3][tid];
    float M = fmaxf(fmaxf(pmax[0][tid], pmax[1][tid]),
                    fmaxf(pmax[2][tid], pmax[3][tid]));
    emb[tid] = S * (1.0f / NPG);
    emb[64 + tid] = M;
  }
  __syncthreads();
  if (tid < 32) {
    float acc = 0.0f;
    for (int k = 0; k < 128; ++k) acc += emb[k] * Wf1[k * 32 + tid];
    z[g * 32 + tid] = acc;
  }
}

// single block: BNf stats over z (G x 32) -> coeffs -> relu -> FC2 -> out
__global__ __launch_bounds__(256) void k_final(const float* __restrict__ z,
                                               const float* __restrict__ gf,
                                               const float* __restrict__ bef,
                                               const float* __restrict__ Wf2,
                                               const float* __restrict__ bf2,
                                               float* __restrict__ out, int G) {
  __shared__ float ss[32], qs[32];
  __shared__ float af[32], cf[32];
  int tid = threadIdx.x;
  if (tid < 32) { ss[tid] = 0.0f; qs[tid] = 0.0f; }
  __syncthreads();
  float s = 0.0f, q = 0.0f;
  for (int i = tid; i < G * 32; i += 256) {
    float v = z[i];
    s += v; q += v * v;
  }
  atomicAdd(&ss[tid & 31], s);
  atomicAdd(&qs[tid & 31], q);
  __syncthreads();
  if (tid < 32) {
    float invG = 1.0f / G;
    float m = ss[tid] * invG;
    float v = qs[tid] * invG - m * m;
    float a = gf[tid] * rsqrtf(v + EPS);
    af[tid] = a;
    cf[tid] = bef[tid] - m * a;
  }
  __syncthreads();
  float w00 = Wf2[0]; // avoid recomputing? just read in loop; tiny anyway
  (void)w00;
  for (int g = tid; g < G; g += 256) {
    float o0 = bf2[0], o1 = bf2[1];
#pragma unroll
    for (int j = 0; j < 32; ++j) {
      float y = fmaxf(0.0f, af[j] * z[g * 32 + j] + cf[j]);
      o0 += y * Wf2[j * 2];
      o1 += y * Wf2[j * 2 + 1];
    }
    out[g * 2] = o0;
    out[g * 2 + 1] = o1;
  }
}

extern "C" void kernel_launch(void* const* d_in, const int* in_sizes, int n_in,
                              void* d_out, int out_size, void* d_ws, size_t ws_size,
                              hipStream_t stream) {
  const float* x   = (const float*)d_in[0];
  const int*   ei  = (const int*)d_in[1];
  const float* ew  = (const float*)d_in[2];
  // d_in[3] = batch (implicit: node/NPG), d_in[5]=b1, d_in[9]=b2, d_in[13]=bf1
  // cancel under training-mode BN and are unused.
  const float* W1  = (const float*)d_in[4];
  const float* g1  = (const float*)d_in[6];
  const float* be1 = (const float*)d_in[7];
  const float* W2  = (const float*)d_in[8];
  const float* g2  = (const float*)d_in[10];
  const float* be2 = (const float*)d_in[11];
  const float* Wf1 = (const float*)d_in[12];
  const float* gf  = (const float*)d_in[14];
  const float* bef = (const float*)d_in[15];
  const float* Wf2 = (const float*)d_in[16];
  const float* bf2 = (const float*)d_in[17];

  int N = in_sizes[3];          // 118784
  int E = in_sizes[2];          // 3801088
  int G = N / NPG;              // 1024

  float* ws    = (float*)d_ws;
  float* stats = ws;            // 256
  float* coef  = ws + 256;      // 256
  float* dinv  = ws + 512;
  float* h1    = dinv + N;
  float* h2    = h1 + (size_t)N * HID;
  float* z     = h2 + (size_t)N * HID2;
  float* out   = (float*)d_out;

  int gemmBlocks = (N + 63) / 64;

  k_deg<<<G, 256, 0, stream>>>(ei, ew, dinv, stats, N, E);
  k_gemm1<<<gemmBlocks, 256, 0, stream>>>(x, W1, h1, N);
  k_scat1<<<G, 256, 0, stream>>>(ei, ew, dinv, h1, stats, N, E);
  k_coef<<<1, 64, 0, stream>>>(stats, stats + 32, g1, be1, coef, coef + 32,
                               1.0f / (float)N, HID);
  k_gemm2<<<gemmBlocks, 256, 0, stream>>>(h1, W2, coef, h2, N);
  k_scat2<<<G, 256, 0, stream>>>(ei, ew, dinv, h2, stats, N, E);
  k_coef<<<1, 64, 0, stream>>>(stats + 64, stats + 128, g2, be2, coef + 64,
                               coef + 128, 1.0f / (float)N, HID2);
  k_pool<<<G, 256, 0, stream>>>(h2, coef, Wf1, z, N);
  k_final<<<1, 256, 0, stream>>>(z, gf, bef, Wf2, bf2, out, G);
}

// Round 2
// 299.136 us; speedup vs baseline: 6.7511x; 6.7511x over previous
//
#include <hip/hip_runtime.h>

#define NPG 116          // nodes per graph
#define DEGC 32          // edges per node
#define EPG (NPG * DEGC) // 3712 edges per graph
#define HID 32
#define HID2 64
#define EPS 1e-5f

#define APAD 120         // A row stride (floats), 16B-aligned rows
#define L1S 33           // l1 row stride (bank-conflict-free column reads)
#define YS  36           // ys row stride (16B-aligned rows)
#define L2S 65           // l2 row stride (bank-conflict-free column reads)

#define FMA4(acc, a, b)                                                        \
  acc.x += (a).x * (b).x; acc.y += (a).y * (b).y;                              \
  acc.z += (a).z * (b).z; acc.w += (a).w * (b).w;

// ---------------------------------------------------------------------------
// ws layout (floats):
//   [0,256)    stats: s1[32] q1[32] s2[64] q2[64]   (memset to 0 each launch)
//   [256,512)  coefs: a1[32] c1[32] a2[64] c2[64]
//   [512, +32N)   h1  (conv1 output)
//   [..,  +64N)   h2  (conv2 output)
//   [..,  +32G)   z   (FC1 pre-BN)
// ---------------------------------------------------------------------------

// Fused: stage x tile -> lin1 = x@W1 -> build normalized A -> h1 = A@lin1
// -> write h1 + BN1 stat partials.  One block per graph.
__global__ __launch_bounds__(256) void k_conv1(const float* __restrict__ x,
                                               const int* __restrict__ ei,
                                               const float* __restrict__ ew,
                                               const float* __restrict__ W1,
                                               float* __restrict__ h1,
                                               float* __restrict__ stats,
                                               int N, int E) {
  __shared__ __align__(16) float A[NPG * APAD];   // first used as x tile
  __shared__ float l1[NPG * L1S];
  __shared__ float degs[NPG];
  __shared__ float ss[HID], qs[HID];
  int g = blockIdx.x, tid = threadIdx.x;
  int nb = g * NPG, e0 = g * EPG;
  const int* rowp = ei;
  const int* colp = ei + E;

  for (int i = tid; i < NPG; i += 256) degs[i] = 1.0f;  // self-loop weight
  if (tid < HID) { ss[tid] = 0.0f; qs[tid] = 0.0f; }
  __syncthreads();

  // phase 1: stage x tile (float4), deg atomics, W1 column -> regs
  {
    const float4* xg = (const float4*)(x + (size_t)nb * 116);
    float4* xs4 = (float4*)A;
    for (int i = tid; i < 116 * 29; i += 256) {
      int r = i / 29, jc = i - r * 29;
      xs4[r * 30 + jc] = xg[i];
    }
    for (int e = tid; e < EPG; e += 256) {
      int d = colp[e0 + e] - nb;
      atomicAdd(&degs[d], ew[e0 + e]);
    }
  }
  int c = tid & 31, rgrp = tid >> 5;  // 8 row groups x 15 rows
  float4 col[29];
#pragma unroll
  for (int kc = 0; kc < 29; ++kc) {
    col[kc].x = W1[(4 * kc + 0) * 32 + c];
    col[kc].y = W1[(4 * kc + 1) * 32 + c];
    col[kc].z = W1[(4 * kc + 2) * 32 + c];
    col[kc].w = W1[(4 * kc + 3) * 32 + c];
  }
  __syncthreads();  // x tile staged, deg atomics done

  for (int i = tid; i < NPG; i += 256) degs[i] = rsqrtf(degs[i]);  // deg>=1

  // gemm1: l1[r][c] = sum_k x[r][k] * W1[k][c]
  const float4* A4 = (const float4*)A;
  for (int m = 0; m < 15; ++m) {
    int r = rgrp * 15 + m;
    if (r < NPG) {
      float4 acc = {0.f, 0.f, 0.f, 0.f};
#pragma unroll
      for (int jc = 0; jc < 29; ++jc) {
        float4 a = A4[r * 30 + jc];
        FMA4(acc, a, col[jc]);
      }
      l1[r * L1S + c] = (acc.x + acc.y) + (acc.z + acc.w);
    }
  }
  __syncthreads();  // all x-tile reads done -> reuse A

  {
    float4 z4 = {0.f, 0.f, 0.f, 0.f};
    float4* Az = (float4*)A;
    for (int i = tid; i < 116 * 30; i += 256) Az[i] = z4;
  }
  __syncthreads();

  // build A:  A[d][s] += dinv[s]*ew*dinv[d];  self loops A[i][i] += dinv[i]^2
  for (int e = tid; e < EPG; e += 256) {
    int eg = e0 + e;
    int s = rowp[eg] - nb, d = colp[eg] - nb;
    atomicAdd(&A[d * APAD + s], degs[s] * ew[eg] * degs[d]);
  }
  for (int i = tid; i < NPG; i += 256)
    atomicAdd(&A[i * APAD + i], degs[i] * degs[i]);
  // reload col regs with this lane's l1 column (l1 complete since last sync)
#pragma unroll
  for (int kc = 0; kc < 29; ++kc) {
    col[kc].x = l1[(4 * kc + 0) * L1S + c];
    col[kc].y = l1[(4 * kc + 1) * L1S + c];
    col[kc].z = l1[(4 * kc + 2) * L1S + c];
    col[kc].w = l1[(4 * kc + 3) * L1S + c];
  }
  __syncthreads();  // A complete

  float s_ = 0.0f, q_ = 0.0f;
  for (int m = 0; m < 15; ++m) {
    int r = rgrp * 15 + m;
    if (r < NPG) {
      float4 acc = {0.f, 0.f, 0.f, 0.f};
#pragma unroll
      for (int jc = 0; jc < 29; ++jc) {
        float4 a = A4[r * 30 + jc];
        FMA4(acc, a, col[jc]);
      }
      float v = (acc.x + acc.y) + (acc.z + acc.w);
      h1[(size_t)(nb + r) * HID + c] = v;
      s_ += v; q_ += v * v;
    }
  }
  atomicAdd(&ss[c], s_);
  atomicAdd(&qs[c], q_);
  __syncthreads();
  if (tid < HID) {
    atomicAdd(&stats[tid], ss[tid]);
    atomicAdd(&stats[32 + tid], qs[tid]);
  }
}

// BN coefficients: a = g*rsqrt(var+eps), c = beta - mean*a
__global__ void k_coef(const float* __restrict__ s, const float* __restrict__ q,
                       const float* __restrict__ gamma, const float* __restrict__ beta,
                       float* __restrict__ a, float* __restrict__ cc,
                       float invN, int C) {
  int c = threadIdx.x;
  if (c < C) {
    float m = s[c] * invN;
    float v = q[c] * invN - m * m;
    float aa = gamma[c] * rsqrtf(v + EPS);
    a[c] = aa;
    cc[c] = beta[c] - m * aa;
  }
}

// Fused: ys = relu(a1*h1+c1) -> lin2 = ys@W2 -> build A -> h2 = A@lin2
// -> write h2 + BN2 stat partials.  One block per graph.
__global__ __launch_bounds__(256) void k_conv2(const float* __restrict__ h1,
                                               const int* __restrict__ ei,
                                               const float* __restrict__ ew,
                                               const float* __restrict__ W2,
                                               const float* __restrict__ coef,
                                               float* __restrict__ h2,
                                               float* __restrict__ stats2,
                                               int N, int E) {
  __shared__ __align__(16) float A[NPG * APAD];
  __shared__ __align__(16) float ys[NPG * YS];
  __shared__ float l2[NPG * L2S];
  __shared__ float degs[NPG];
  __shared__ float ss[HID2], qs[HID2];
  int g = blockIdx.x, tid = threadIdx.x;
  int nb = g * NPG, e0 = g * EPG;
  const int* rowp = ei;
  const int* colp = ei + E;

  for (int i = tid; i < NPG; i += 256) degs[i] = 1.0f;
  if (tid < HID2) { ss[tid] = 0.0f; qs[tid] = 0.0f; }
  __syncthreads();

  // phase 1: stage ys = relu(a1*h1+c1), deg atomics, zero A, W2 col -> regs
  {
    const float4* hg = (const float4*)(h1 + (size_t)nb * HID);
    const float4* a4p = (const float4*)coef;         // a1[32]
    const float4* c4p = (const float4*)(coef + 32);  // c1[32]
    float4* ys4 = (float4*)ys;
    for (int i = tid; i < 116 * 8; i += 256) {
      int r = i >> 3, kc = i & 7;
      float4 hv = hg[i];
      float4 av = a4p[kc], cv = c4p[kc];
      float4 y;
      y.x = fmaxf(0.f, av.x * hv.x + cv.x);
      y.y = fmaxf(0.f, av.y * hv.y + cv.y);
      y.z = fmaxf(0.f, av.z * hv.z + cv.z);
      y.w = fmaxf(0.f, av.w * hv.w + cv.w);
      ys4[r * 9 + kc] = y;
    }
    for (int e = tid; e < EPG; e += 256) {
      int d = colp[e0 + e] - nb;
      atomicAdd(&degs[d], ew[e0 + e]);
    }
    float4 z4 = {0.f, 0.f, 0.f, 0.f};
    float4* Az = (float4*)A;
    for (int i = tid; i < 116 * 30; i += 256) Az[i] = z4;
  }
  int c = tid & 63, rgrp = tid >> 6;  // 4 row groups x 29 rows
  float4 w2c[8];
#pragma unroll
  for (int kc = 0; kc < 8; ++kc) {
    w2c[kc].x = W2[(4 * kc + 0) * 64 + c];
    w2c[kc].y = W2[(4 * kc + 1) * 64 + c];
    w2c[kc].z = W2[(4 * kc + 2) * 64 + c];
    w2c[kc].w = W2[(4 * kc + 3) * 64 + c];
  }
  __syncthreads();

  for (int i = tid; i < NPG; i += 256) degs[i] = rsqrtf(degs[i]);
  __syncthreads();  // dinv ready

  // A-build atomics (latency) interleaved with gemm2 (compute)
  for (int e = tid; e < EPG; e += 256) {
    int eg = e0 + e;
    int s = rowp[eg] - nb, d = colp[eg] - nb;
    atomicAdd(&A[d * APAD + s], degs[s] * ew[eg] * degs[d]);
  }
  for (int i = tid; i < NPG; i += 256)
    atomicAdd(&A[i * APAD + i], degs[i] * degs[i]);

  const float4* ys4 = (const float4*)ys;
  for (int m = 0; m < 29; ++m) {
    int r = rgrp * 29 + m;
    float4 acc = {0.f, 0.f, 0.f, 0.f};
#pragma unroll
    for (int kc = 0; kc < 8; ++kc) {
      float4 a = ys4[r * 9 + kc];
      FMA4(acc, a, w2c[kc]);
    }
    l2[r * L2S + c] = (acc.x + acc.y) + (acc.z + acc.w);
  }
  __syncthreads();  // A + l2 complete

  float4 col[29];
#pragma unroll
  for (int kc = 0; kc < 29; ++kc) {
    col[kc].x = l2[(4 * kc + 0) * L2S + c];
    col[kc].y = l2[(4 * kc + 1) * L2S + c];
    col[kc].z = l2[(4 * kc + 2) * L2S + c];
    col[kc].w = l2[(4 * kc + 3) * L2S + c];
  }
  const float4* A4 = (const float4*)A;
  float s_ = 0.0f, q_ = 0.0f;
  for (int m = 0; m < 29; ++m) {
    int r = rgrp * 29 + m;
    float4 acc = {0.f, 0.f, 0.f, 0.f};
#pragma unroll
    for (int jc = 0; jc < 29; ++jc) {
      float4 a = A4[r * 30 + jc];
      FMA4(acc, a, col[jc]);
    }
    float v = (acc.x + acc.y) + (acc.z + acc.w);
    h2[(size_t)(nb + r) * HID2 + c] = v;
    s_ += v; q_ += v * v;
  }
  atomicAdd(&ss[c], s_);
  atomicAdd(&qs[c], q_);
  __syncthreads();
  if (tid < HID2) {
    atomicAdd(&stats2[tid], ss[tid]);
    atomicAdd(&stats2[64 + tid], qs[tid]);
  }
}

// per-graph BN2+relu, mean/max pool, FC1 (emb[128] @ Wf1[128x32]) -> z
__global__ __launch_bounds__(256) void k_pool(const float* __restrict__ h2,
                                              const float* __restrict__ coef,
                                              const float* __restrict__ Wf1,
                                              float* __restrict__ z, int N) {
  __shared__ float emb[128];
  __shared__ float psum[4][64];
  __shared__ float pmax[4][64];
  int g = blockIdx.x, tid = threadIdx.x;
  int c = tid & 63, grp = tid >> 6;
  float a = coef[64 + c], b = coef[128 + c];
  long nb = (long)g * NPG;
  float s = 0.0f, mx = -1e30f;
  for (int n = grp; n < NPG; n += 4) {
    float v = h2[(nb + n) * 64 + c];
    float y = fmaxf(0.0f, a * v + b);
    s += y; mx = fmaxf(mx, y);
  }
  psum[grp][c] = s; pmax[grp][c] = mx;
  __syncthreads();
  if (tid < 64) {
    float S = psum[0][tid] + psum[1][tid] + psum[2][tid] + psum[3][tid];
    float M = fmaxf(fmaxf(pmax[0][tid], pmax[1][tid]),
                    fmaxf(pmax[2][tid], pmax[3][tid]));
    emb[tid] = S * (1.0f / NPG);
    emb[64 + tid] = M;
  }
  __syncthreads();
  if (tid < 32) {
    float acc = 0.0f;
    for (int k = 0; k < 128; ++k) acc += emb[k] * Wf1[k * 32 + tid];
    z[g * 32 + tid] = acc;
  }
}

// single block: BNf stats over z (G x 32) -> coeffs -> relu -> FC2 -> out
__global__ __launch_bounds__(256) void k_final(const float* __restrict__ z,
                                               const float* __restrict__ gf,
                                               const float* __restrict__ bef,
                                               const float* __restrict__ Wf2,
                                               const float* __restrict__ bf2,
                                               float* __restrict__ out, int G) {
  __shared__ float ss[32], qs[32];
  __shared__ float af[32], cf[32];
  int tid = threadIdx.x;
  if (tid < 32) { ss[tid] = 0.0f; qs[tid] = 0.0f; }
  __syncthreads();
  float s = 0.0f, q = 0.0f;
  for (int i = tid; i < G * 32; i += 256) {
    float v = z[i];
    s += v; q += v * v;
  }
  atomicAdd(&ss[tid & 31], s);
  atomicAdd(&qs[tid & 31], q);
  __syncthreads();
  if (tid < 32) {
    float invG = 1.0f / G;
    float m = ss[tid] * invG;
    float v = qs[tid] * invG - m * m;
    float a = gf[tid] * rsqrtf(v + EPS);
    af[tid] = a;
    cf[tid] = bef[tid] - m * a;
  }
  __syncthreads();
  for (int g = tid; g < G; g += 256) {
    float o0 = bf2[0], o1 = bf2[1];
#pragma unroll
    for (int j = 0; j < 32; ++j) {
      float y = fmaxf(0.0f, af[j] * z[g * 32 + j] + cf[j]);
      o0 += y * Wf2[j * 2];
      o1 += y * Wf2[j * 2 + 1];
    }
    out[g * 2] = o0;
    out[g * 2 + 1] = o1;
  }
}

extern "C" void kernel_launch(void* const* d_in, const int* in_sizes, int n_in,
                              void* d_out, int out_size, void* d_ws, size_t ws_size,
                              hipStream_t stream) {
  const float* x   = (const float*)d_in[0];
  const int*   ei  = (const int*)d_in[1];
  const float* ew  = (const float*)d_in[2];
  // d_in[3]=batch (implicit), d_in[5]=b1, d_in[9]=b2, d_in[13]=bf1 cancel
  // under training-mode BN and are unused.
  const float* W1  = (const float*)d_in[4];
  const float* g1  = (const float*)d_in[6];
  const float* be1 = (const float*)d_in[7];
  const float* W2  = (const float*)d_in[8];
  const float* g2  = (const float*)d_in[10];
  const float* be2 = (const float*)d_in[11];
  const float* Wf1 = (const float*)d_in[12];
  const float* gf  = (const float*)d_in[14];
  const float* bef = (const float*)d_in[15];
  const float* Wf2 = (const float*)d_in[16];
  const float* bf2 = (const float*)d_in[17];

  int N = in_sizes[3];   // 118784
  int E = in_sizes[2];   // 3801088
  int G = N / NPG;       // 1024

  float* ws    = (float*)d_ws;
  float* stats = ws;         // 256
  float* coef  = ws + 256;   // 256
  float* h1    = ws + 512;
  float* h2    = h1 + (size_t)N * HID;
  float* z     = h2 + (size_t)N * HID2;
  float* out   = (float*)d_out;

  hipMemsetAsync(stats, 0, 256 * sizeof(float), stream);
  k_conv1<<<G, 256, 0, stream>>>(x, ei, ew, W1, h1, stats, N, E);
  k_coef<<<1, 64, 0, stream>>>(stats, stats + 32, g1, be1, coef, coef + 32,
                               1.0f / (float)N, HID);
  k_conv2<<<G, 256, 0, stream>>>(h1, ei, ew, W2, coef, h2, stats + 64, N, E);
  k_coef<<<1, 64, 0, stream>>>(stats + 64, stats + 128, g2, be2, coef + 64,
                               coef + 128, 1.0f / (float)N, HID2);
  k_pool<<<G, 256, 0, stream>>>(h2, coef, Wf1, z, N);
  k_final<<<1, 256, 0, stream>>>(z, gf, bef, Wf2, bf2, out, G);
}